// Round 6
// baseline (519.380 us; speedup 1.0000x reference)
//
#include <hip/hip_runtime.h>
#include <hip/hip_bf16.h>

#define D 50
#define PAD 52                      // padded row stride (13 x float4)
#define GLAM 0.05555555555555555f   // gamma * lambda = (1/(2*0.9)) * 0.1
#define SCAN_B 1024
#define MASK44 ((1ULL << 44) - 1)
#define FIXS 16777216.0f            // 2^24 fixed-point scale
#define INV_FIXS (1.0f / 16777216.0f)

typedef unsigned long long u64;

// ---- init: packed (cnt=0, ideg=1.0 fixed) for self loop; odeg = 1.0 ----
__global__ void k_init(u64* __restrict__ pkdeg, float* __restrict__ odeg, int n) {
    int i = blockIdx.x * blockDim.x + threadIdx.x;
    if (i < n) { pkdeg[i] = (u64)(1 << 24); odeg[i] = 1.0f; }
}

// ---- weighted degrees + dst histogram; atomic RETURN gives edge rank ----
__global__ void k_deg_hist(const float* __restrict__ ew, const int* __restrict__ src,
                           const int* __restrict__ dst, u64* __restrict__ pkdeg,
                           float* __restrict__ odeg, int* __restrict__ rank, int e) {
    int i = blockIdx.x * blockDim.x + threadIdx.x;
    if (i < e) {
        float w = ew[i];
        int s = src[i], t = dst[i];
        u64 pk = (1ULL << 44) + (u64)(w * FIXS + 0.5f);
        u64 old = atomicAdd(&pkdeg[t], pk);
        rank[i] = (int)(old >> 44);          // position within dst bucket
        atomicAdd(&odeg[s], w);
    }
}

// ---- unpack: cnt, isi = rsqrt(ideg); iso = rsqrt(odeg) in place ----
__global__ void k_post(const u64* __restrict__ pkdeg, float* __restrict__ odeg,
                       float* __restrict__ isi, int* __restrict__ cnt, int n) {
    int i = blockIdx.x * blockDim.x + threadIdx.x;
    if (i < n) {
        u64 p = pkdeg[i];
        cnt[i] = (int)(p >> 44);
        isi[i] = rsqrtf((float)(p & MASK44) * INV_FIXS);
        odeg[i] = rsqrtf(odeg[i]);   // becomes iso
    }
}

// ---- exclusive scan of cnt -> rowptr ----
__global__ void k_scan1(const int* __restrict__ cnt, int* __restrict__ rowptr,
                        int* __restrict__ bsum, int n) {
    __shared__ int s[SCAN_B];
    int i = blockIdx.x * SCAN_B + threadIdx.x;
    int v = (i < n) ? cnt[i] : 0;
    s[threadIdx.x] = v; __syncthreads();
    for (int off = 1; off < SCAN_B; off <<= 1) {
        int t = (threadIdx.x >= (unsigned)off) ? s[threadIdx.x - off] : 0;
        __syncthreads();
        s[threadIdx.x] += t; __syncthreads();
    }
    if (i < n) rowptr[i] = s[threadIdx.x] - v;          // exclusive
    if (threadIdx.x == SCAN_B - 1) bsum[blockIdx.x] = s[threadIdx.x];
}

__global__ void k_scan2(int* __restrict__ bsum, int nb) {
    __shared__ int s[SCAN_B];
    int v = (threadIdx.x < (unsigned)nb) ? bsum[threadIdx.x] : 0;
    s[threadIdx.x] = v; __syncthreads();
    for (int off = 1; off < SCAN_B; off <<= 1) {
        int t = (threadIdx.x >= (unsigned)off) ? s[threadIdx.x - off] : 0;
        __syncthreads();
        s[threadIdx.x] += t; __syncthreads();
    }
    if (threadIdx.x < (unsigned)nb) bsum[threadIdx.x] = s[threadIdx.x] - v;  // exclusive
}

__global__ void k_scan3(int* __restrict__ rowptr, const int* __restrict__ bsum, int n) {
    int i = blockIdx.x * SCAN_B + threadIdx.x;
    if (i < n) rowptr[i] += bsum[blockIdx.x];
}

// ---- scatter edges into dst-CSR: NO atomics (rank from histogram) ----
__global__ void k_scatter(const float* __restrict__ ew, const int* __restrict__ src,
                          const int* __restrict__ dst, const float* __restrict__ iso,
                          const float* __restrict__ isi, const int* __restrict__ rowptr,
                          const int* __restrict__ rank, u64* __restrict__ pe, int e) {
    int i = blockIdx.x * blockDim.x + threadIdx.x;
    if (i < e) {
        int s = src[i], t = dst[i];
        int pos = rowptr[t] + rank[i];
        float wv = ew[i] * iso[s] * isi[t];
        pe[pos] = (u64)(unsigned)s | ((u64)__float_as_uint(wv) << 32);
    }
}

// ---- pad feat (stride 50) -> xpad (stride 52, zeros in pad cols) ----
__global__ void k_pad(const float* __restrict__ feat, float* __restrict__ xp, int n) {
    int i = blockIdx.x * blockDim.x + threadIdx.x;
    if (i < n * PAD) {
        int node = i / PAD, col = i - node * PAD;
        xp[i] = (col < D) ? feat[node * D + col] : 0.0f;
    }
}

// ---- fused iteration: 52-lane vectorized gather (4 edges x 13 float4) ----
__global__ void k_iter(const int* __restrict__ rowptr, const int* __restrict__ cnt,
                       const u64* __restrict__ pe, const float* __restrict__ xin,
                       const float* __restrict__ feat, const float* __restrict__ iso,
                       const float* __restrict__ isi, float* __restrict__ xout,
                       int n, int final_iter) {
    int lane = threadIdx.x & 63;
    int node = blockIdx.x * (blockDim.x >> 6) + (threadIdx.x >> 6);
    if (node >= n) return;

    int t4 = lane / 13;              // edge slot 0..3 (lanes >= 52: unused)
    int ci = lane - t4 * 13;         // float4 chunk index 0..12
    bool act = (lane < 52);

    float ax = 0.f, ay = 0.f, az = 0.f, aw = 0.f;
    int beg = rowptr[node], m = cnt[node];

    for (int j0 = 0; j0 < m; j0 += 64) {
        int mm = m - j0; if (mm > 64) mm = 64;
        int c = 0; float ww = 0.0f;
        if (lane < mm) {
            u64 p = pe[beg + j0 + lane];
            c  = (int)(unsigned)(p & 0xffffffffULL);
            ww = __uint_as_float((unsigned)(p >> 32));
        }
        for (int jj = 0; jj < mm; jj += 4) {
            int idx = (jj + t4) & 63;
            int   s = __shfl(c,  idx, 64);   // pad slots: c=0,w=0 -> harmless
            float w = __shfl(ww, idx, 64);
            if (act) {
                const float4 xr = *(const float4*)(xin + (size_t)s * PAD + (ci << 2));
                ax = fmaf(w, xr.x, ax); ay = fmaf(w, xr.y, ay);
                az = fmaf(w, xr.z, az); aw = fmaf(w, xr.w, aw);
            }
        }
    }

    // combine edge-slot groups: lane L(<13) sums lanes L, L+13, L+26, L+39
    ax += __shfl(ax, (lane + 26) & 63, 64); ay += __shfl(ay, (lane + 26) & 63, 64);
    az += __shfl(az, (lane + 26) & 63, 64); aw += __shfl(aw, (lane + 26) & 63, 64);
    ax += __shfl(ax, (lane + 13) & 63, 64); ay += __shfl(ay, (lane + 13) & 63, 64);
    az += __shfl(az, (lane + 13) & 63, 64); aw += __shfl(aw, (lane + 13) & 63, 64);

    float selfw = iso[node] * isi[node];
    float fx = 0.f, fy = 0.f, fz = 0.f, fw = 0.f;
    float dx = 0.f, dy = 0.f, dz = 0.f, dw = 0.f;
    if (lane < 13) {
        const float4 xs = *(const float4*)(xin + (size_t)node * PAD + (ci << 2));
        ax = fmaf(selfw, xs.x, ax); ay = fmaf(selfw, xs.y, ay);
        az = fmaf(selfw, xs.z, az); aw = fmaf(selfw, xs.w, aw);
        const float2 f01 = *(const float2*)(feat + (size_t)node * D + (ci << 2));
        fx = f01.x; fy = f01.y;
        if (ci < 12) {
            const float2 f23 = *(const float2*)(feat + (size_t)node * D + (ci << 2) + 2);
            fz = f23.x; fw = f23.y;
        }
        dx = ax - fx; dy = ay - fy;
        dz = (ci < 12) ? (az - fz) : 0.0f;
        dw = (ci < 12) ? (aw - fw) : 0.0f;
    }
    float ssum = (lane < 13) ? (dx * dx + dy * dy + dz * dz + dw * dw) : 0.0f;
    ssum += __shfl_xor(ssum, 1, 16);
    ssum += __shfl_xor(ssum, 2, 16);
    ssum += __shfl_xor(ssum, 4, 16);
    ssum += __shfl_xor(ssum, 8, 16);
    float norm = sqrtf(ssum);
    float sc = (norm > 0.0f) ? fmaxf(norm - GLAM, 0.0f) / norm : 0.0f;

    if (lane < 13) {
        float ox = fx + sc * dx, oy = fy + sc * dy;
        float oz = fz + sc * dz, ow = fw + sc * dw;
        if (!final_iter) {
            float4 o;
            o.x = ox; o.y = oy;
            o.z = (ci < 12) ? oz : 0.0f;
            o.w = (ci < 12) ? ow : 0.0f;
            *(float4*)(xout + (size_t)node * PAD + (ci << 2)) = o;
        } else {
            float2 o01; o01.x = ox; o01.y = oy;
            *(float2*)(xout + (size_t)node * D + (ci << 2)) = o01;
            if (ci < 12) {
                float2 o23; o23.x = oz; o23.y = ow;
                *(float2*)(xout + (size_t)node * D + (ci << 2) + 2) = o23;
            }
        }
    }
}

extern "C" void kernel_launch(void* const* d_in, const int* in_sizes, int n_in,
                              void* d_out, int out_size, void* d_ws, size_t ws_size,
                              hipStream_t stream) {
    const float* feat = (const float*)d_in[0];
    const float* ew   = (const float*)d_in[1];
    const int* src = (const int*)d_in[2];
    const int* dst = (const int*)d_in[3];

    const int nd = in_sizes[0];      // N * D
    const int n  = nd / D;           // N nodes
    const int e  = in_sizes[1];      // E edges
    const int np = n * PAD;          // padded feature count

    // workspace layout (8B-aligned arrays first)
    u64*   pkdeg  = (u64*)d_ws;              // n
    u64*   pe     = pkdeg + n;               // e  (packed col|wv)
    float* xpA    = (float*)(pe + e);        // np
    float* xpB    = xpA + np;                // np
    float* odeg   = xpB + np;                // n  -> iso after k_post
    float* isi    = odeg + n;                // n
    int*   cnt    = (int*)(isi + n);         // n
    int*   rowptr = cnt + n;                 // n
    int*   rank   = rowptr + n;              // e
    int*   bsum   = rank + e;                // 128
    float* out    = (float*)d_out;

    const int B = 256;
    const int gN = (n + B - 1) / B;
    const int gE = (e + B - 1) / B;
    const int gP = (np + B - 1) / B;
    const int NB = (n + SCAN_B - 1) / SCAN_B;

    k_init<<<gN, B, 0, stream>>>(pkdeg, odeg, n);
    k_deg_hist<<<gE, B, 0, stream>>>(ew, src, dst, pkdeg, odeg, rank, e);
    k_post<<<gN, B, 0, stream>>>(pkdeg, odeg, isi, cnt, n);
    k_scan1<<<NB, SCAN_B, 0, stream>>>(cnt, rowptr, bsum, n);
    k_scan2<<<1, SCAN_B, 0, stream>>>(bsum, NB);
    k_scan3<<<NB, SCAN_B, 0, stream>>>(rowptr, bsum, n);
    k_scatter<<<gE, B, 0, stream>>>(ew, src, dst, odeg, isi, rowptr, rank, pe, e);
    k_pad<<<gP, B, 0, stream>>>(feat, xpA, n);

    const int wavesPerBlock = B / 64;            // 4
    const int iterGrid = (n + wavesPerBlock - 1) / wavesPerBlock;

    // iter1: xpA -> xpB ; iter2: xpB -> xpA ; iter3: xpA -> d_out (unpadded)
    k_iter<<<iterGrid, B, 0, stream>>>(rowptr, cnt, pe, xpA, feat, odeg, isi, xpB, n, 0);
    k_iter<<<iterGrid, B, 0, stream>>>(rowptr, cnt, pe, xpB, feat, odeg, isi, xpA, n, 0);
    k_iter<<<iterGrid, B, 0, stream>>>(rowptr, cnt, pe, xpA, feat, odeg, isi, out, n, 1);
}

// Round 7
// 476.530 us; speedup vs baseline: 1.0899x; 1.0899x over previous
//
#include <hip/hip_runtime.h>
#include <hip/hip_bf16.h>
#include <hip/hip_fp16.h>

#define D 50
#define PAD 52                      // padded row stride in elements (13 x 4)
#define GLAM 0.05555555555555555f   // gamma * lambda = (1/(2*0.9)) * 0.1
#define SCAN_B 1024
#define MASK44 ((1ULL << 44) - 1)
#define FIXS 16777216.0f            // 2^24 fixed-point scale
#define INV_FIXS (1.0f / 16777216.0f)

typedef unsigned long long u64;

// ---- init: packed (cnt=0, ideg=1.0 fixed) for self loop; odeg = 1.0 ----
__global__ void k_init(u64* __restrict__ pkdeg, float* __restrict__ odeg, int n) {
    int i = blockIdx.x * blockDim.x + threadIdx.x;
    if (i < n) { pkdeg[i] = (u64)(1 << 24); odeg[i] = 1.0f; }
}

// ---- weighted degrees + dst histogram (atomic return = rank), fused with
//      feat fp32 -> fp16 padded convert (separate block range) ----
__global__ void k_deg_hist_pad(const float* __restrict__ ew, const int* __restrict__ src,
                               const int* __restrict__ dst, u64* __restrict__ pkdeg,
                               float* __restrict__ odeg, int* __restrict__ rank,
                               const float* __restrict__ feat, __half* __restrict__ xp,
                               int e, int n, int gE) {
    if ((int)blockIdx.x < gE) {
        int i = blockIdx.x * blockDim.x + threadIdx.x;
        if (i < e) {
            float w = ew[i];
            int s = src[i], t = dst[i];
            u64 pk = (1ULL << 44) + (u64)(w * FIXS + 0.5f);
            u64 old = atomicAdd(&pkdeg[t], pk);
            rank[i] = (int)(old >> 44);
            atomicAdd(&odeg[s], w);
        }
    } else {
        int i = (blockIdx.x - gE) * blockDim.x + threadIdx.x;
        if (i < n * PAD) {
            int node = i / PAD, col = i - node * PAD;
            xp[i] = (col < D) ? __float2half_rn(feat[node * D + col]) : __half(0.0f);
        }
    }
}

// ---- unpack: cnt, isi = rsqrt(ideg); iso = rsqrt(odeg) in place ----
__global__ void k_post(const u64* __restrict__ pkdeg, float* __restrict__ odeg,
                       float* __restrict__ isi, int* __restrict__ cnt, int n) {
    int i = blockIdx.x * blockDim.x + threadIdx.x;
    if (i < n) {
        u64 p = pkdeg[i];
        cnt[i] = (int)(p >> 44);
        isi[i] = rsqrtf((float)(p & MASK44) * INV_FIXS);
        odeg[i] = rsqrtf(odeg[i]);   // becomes iso
    }
}

// ---- exclusive scan of cnt -> rowptr ----
__global__ void k_scan1(const int* __restrict__ cnt, int* __restrict__ rowptr,
                        int* __restrict__ bsum, int n) {
    __shared__ int s[SCAN_B];
    int i = blockIdx.x * SCAN_B + threadIdx.x;
    int v = (i < n) ? cnt[i] : 0;
    s[threadIdx.x] = v; __syncthreads();
    for (int off = 1; off < SCAN_B; off <<= 1) {
        int t = (threadIdx.x >= (unsigned)off) ? s[threadIdx.x - off] : 0;
        __syncthreads();
        s[threadIdx.x] += t; __syncthreads();
    }
    if (i < n) rowptr[i] = s[threadIdx.x] - v;          // exclusive
    if (threadIdx.x == SCAN_B - 1) bsum[blockIdx.x] = s[threadIdx.x];
}

__global__ void k_scan2(int* __restrict__ bsum, int nb) {
    __shared__ int s[SCAN_B];
    int v = (threadIdx.x < (unsigned)nb) ? bsum[threadIdx.x] : 0;
    s[threadIdx.x] = v; __syncthreads();
    for (int off = 1; off < SCAN_B; off <<= 1) {
        int t = (threadIdx.x >= (unsigned)off) ? s[threadIdx.x - off] : 0;
        __syncthreads();
        s[threadIdx.x] += t; __syncthreads();
    }
    if (threadIdx.x < (unsigned)nb) bsum[threadIdx.x] = s[threadIdx.x] - v;  // exclusive
}

__global__ void k_scan3(int* __restrict__ rowptr, const int* __restrict__ bsum, int n) {
    int i = blockIdx.x * SCAN_B + threadIdx.x;
    if (i < n) rowptr[i] += bsum[blockIdx.x];
}

// ---- scatter edges into dst-CSR: NO atomics (rank from histogram) ----
__global__ void k_scatter(const float* __restrict__ ew, const int* __restrict__ src,
                          const int* __restrict__ dst, const float* __restrict__ iso,
                          const float* __restrict__ isi, const int* __restrict__ rowptr,
                          const int* __restrict__ rank, u64* __restrict__ pe, int e) {
    int i = blockIdx.x * blockDim.x + threadIdx.x;
    if (i < e) {
        int s = src[i], t = dst[i];
        int pos = rowptr[t] + rank[i];
        float wv = ew[i] * iso[s] * isi[t];
        pe[pos] = (u64)(unsigned)s | ((u64)__float_as_uint(wv) << 32);
    }
}

// ---- fused iteration: fp16 x gather (4 edges x 13 lanes x 8B) + prox ----
__global__ void k_iter(const int* __restrict__ rowptr, const int* __restrict__ cnt,
                       const u64* __restrict__ pe, const __half* __restrict__ xin,
                       const float* __restrict__ feat, const float* __restrict__ iso,
                       const float* __restrict__ isi, __half* __restrict__ hout,
                       float* __restrict__ fout, int n, int final_iter) {
    int lane = threadIdx.x & 63;
    int node = blockIdx.x * (blockDim.x >> 6) + (threadIdx.x >> 6);
    if (node >= n) return;

    int t4 = lane / 13;              // edge slot 0..3 (lanes >= 52: unused)
    int ci = lane - t4 * 13;         // 4-feature chunk index 0..12
    bool act = (lane < 52);

    float ax = 0.f, ay = 0.f, az = 0.f, aw = 0.f;
    int beg = rowptr[node], m = cnt[node];

    for (int j0 = 0; j0 < m; j0 += 64) {
        int mm = m - j0; if (mm > 64) mm = 64;
        int c = 0; float ww = 0.0f;
        if (lane < mm) {
            u64 p = pe[beg + j0 + lane];
            c  = (int)(unsigned)(p & 0xffffffffULL);
            ww = __uint_as_float((unsigned)(p >> 32));
        }
        for (int jj = 0; jj < mm; jj += 4) {
            int idx = (jj + t4) & 63;
            int   s = __shfl(c,  idx, 64);   // pad slots: c=0,w=0 -> harmless
            float w = __shfl(ww, idx, 64);
            if (act) {
                uint2 u = *(const uint2*)(xin + (size_t)s * PAD + (ci << 2));
                __half2 h0 = *(__half2*)&u.x;
                __half2 h1 = *(__half2*)&u.y;
                float2 a0 = __half22float2(h0);
                float2 a1 = __half22float2(h1);
                ax = fmaf(w, a0.x, ax); ay = fmaf(w, a0.y, ay);
                az = fmaf(w, a1.x, az); aw = fmaf(w, a1.y, aw);
            }
        }
    }

    // combine edge-slot groups: lane L(<13) sums lanes L, L+13, L+26, L+39
    ax += __shfl(ax, (lane + 26) & 63, 64); ay += __shfl(ay, (lane + 26) & 63, 64);
    az += __shfl(az, (lane + 26) & 63, 64); aw += __shfl(aw, (lane + 26) & 63, 64);
    ax += __shfl(ax, (lane + 13) & 63, 64); ay += __shfl(ay, (lane + 13) & 63, 64);
    az += __shfl(az, (lane + 13) & 63, 64); aw += __shfl(aw, (lane + 13) & 63, 64);

    float selfw = iso[node] * isi[node];
    float fx = 0.f, fy = 0.f, fz = 0.f, fw = 0.f;
    float dx = 0.f, dy = 0.f, dz = 0.f, dw = 0.f;
    if (lane < 13) {
        uint2 u = *(const uint2*)(xin + (size_t)node * PAD + (ci << 2));
        __half2 h0 = *(__half2*)&u.x;
        __half2 h1 = *(__half2*)&u.y;
        float2 s0 = __half22float2(h0);
        float2 s1 = __half22float2(h1);
        ax = fmaf(selfw, s0.x, ax); ay = fmaf(selfw, s0.y, ay);
        az = fmaf(selfw, s1.x, az); aw = fmaf(selfw, s1.y, aw);
        const float2 f01 = *(const float2*)(feat + (size_t)node * D + (ci << 2));
        fx = f01.x; fy = f01.y;
        if (ci < 12) {
            const float2 f23 = *(const float2*)(feat + (size_t)node * D + (ci << 2) + 2);
            fz = f23.x; fw = f23.y;
        }
        dx = ax - fx; dy = ay - fy;
        dz = (ci < 12) ? (az - fz) : 0.0f;
        dw = (ci < 12) ? (aw - fw) : 0.0f;
    }
    float ssum = (lane < 13) ? (dx * dx + dy * dy + dz * dz + dw * dw) : 0.0f;
    ssum += __shfl_xor(ssum, 1, 16);
    ssum += __shfl_xor(ssum, 2, 16);
    ssum += __shfl_xor(ssum, 4, 16);
    ssum += __shfl_xor(ssum, 8, 16);
    float norm = sqrtf(ssum);
    float sc = (norm > 0.0f) ? fmaxf(norm - GLAM, 0.0f) / norm : 0.0f;

    if (lane < 13) {
        float ox = fx + sc * dx, oy = fy + sc * dy;
        float oz = fz + sc * dz, ow = fw + sc * dw;   // ci==12: dz=dw=fz=fw=0 -> 0
        if (!final_iter) {
            __half2 o0 = __float22half2_rn(make_float2(ox, oy));
            __half2 o1 = __float22half2_rn(make_float2(oz, ow));
            uint2 u;
            u.x = *(unsigned*)&o0;
            u.y = *(unsigned*)&o1;
            *(uint2*)(hout + (size_t)node * PAD + (ci << 2)) = u;
        } else {
            float2 o01; o01.x = ox; o01.y = oy;
            *(float2*)(fout + (size_t)node * D + (ci << 2)) = o01;
            if (ci < 12) {
                float2 o23; o23.x = oz; o23.y = ow;
                *(float2*)(fout + (size_t)node * D + (ci << 2) + 2) = o23;
            }
        }
    }
}

extern "C" void kernel_launch(void* const* d_in, const int* in_sizes, int n_in,
                              void* d_out, int out_size, void* d_ws, size_t ws_size,
                              hipStream_t stream) {
    const float* feat = (const float*)d_in[0];
    const float* ew   = (const float*)d_in[1];
    const int* src = (const int*)d_in[2];
    const int* dst = (const int*)d_in[3];

    const int nd = in_sizes[0];      // N * D
    const int n  = nd / D;           // N nodes
    const int e  = in_sizes[1];      // E edges
    const int np = n * PAD;          // padded fp16 element count

    // workspace layout (8B-aligned arrays first)
    u64*    pkdeg  = (u64*)d_ws;             // n
    u64*    pe     = pkdeg + n;              // e  (packed col|wv)
    __half* xpA    = (__half*)(pe + e);      // np (fp16)
    __half* xpB    = xpA + np;               // np (fp16)
    float*  odeg   = (float*)(xpB + np);     // n  -> iso after k_post
    float*  isi    = odeg + n;               // n
    int*    cnt    = (int*)(isi + n);        // n
    int*    rowptr = cnt + n;                // n
    int*    rank   = rowptr + n;             // e
    int*    bsum   = rank + e;               // 128
    float*  out    = (float*)d_out;

    const int B = 256;
    const int gN = (n + B - 1) / B;
    const int gE = (e + B - 1) / B;
    const int gP = (np + B - 1) / B;
    const int NB = (n + SCAN_B - 1) / SCAN_B;

    k_init<<<gN, B, 0, stream>>>(pkdeg, odeg, n);
    k_deg_hist_pad<<<gE + gP, B, 0, stream>>>(ew, src, dst, pkdeg, odeg, rank,
                                              feat, xpA, e, n, gE);
    k_post<<<gN, B, 0, stream>>>(pkdeg, odeg, isi, cnt, n);
    k_scan1<<<NB, SCAN_B, 0, stream>>>(cnt, rowptr, bsum, n);
    k_scan2<<<1, SCAN_B, 0, stream>>>(bsum, NB);
    k_scan3<<<NB, SCAN_B, 0, stream>>>(rowptr, bsum, n);
    k_scatter<<<gE, B, 0, stream>>>(ew, src, dst, odeg, isi, rowptr, rank, pe, e);

    const int wavesPerBlock = B / 64;            // 4
    const int iterGrid = (n + wavesPerBlock - 1) / wavesPerBlock;

    // iter1: xpA -> xpB ; iter2: xpB -> xpA ; iter3: xpA -> d_out (fp32)
    k_iter<<<iterGrid, B, 0, stream>>>(rowptr, cnt, pe, xpA, feat, odeg, isi, xpB, out, n, 0);
    k_iter<<<iterGrid, B, 0, stream>>>(rowptr, cnt, pe, xpB, feat, odeg, isi, xpA, out, n, 0);
    k_iter<<<iterGrid, B, 0, stream>>>(rowptr, cnt, pe, xpA, feat, odeg, isi, xpA, out, n, 1);
}

// Round 8
// 455.016 us; speedup vs baseline: 1.1415x; 1.0473x over previous
//
#include <hip/hip_runtime.h>
#include <hip/hip_bf16.h>
#include <hip/hip_fp16.h>

#define D 50
#define PADH 64                     // fp16 row stride: 128 B = 2 aligned 64B lines
#define GLAM 0.05555555555555555f   // gamma * lambda = (1/(2*0.9)) * 0.1
#define SCAN_B 1024
#define MASK44 ((1ULL << 44) - 1)
#define FIXS 16777216.0f            // 2^24 fixed-point scale
#define INV_FIXS (1.0f / 16777216.0f)

typedef unsigned long long u64;

// ---- init: packed (cnt=0, ideg=1.0 fixed) for self loop; odeg = 1.0 ----
__global__ void k_init(u64* __restrict__ pkdeg, float* __restrict__ odeg, int n) {
    int i = blockIdx.x * blockDim.x + threadIdx.x;
    if (i < n) { pkdeg[i] = (u64)(1 << 24); odeg[i] = 1.0f; }
}

// ---- weighted degrees + dst histogram; atomic RETURN gives edge rank ----
__global__ void k_deg_hist(const float* __restrict__ ew, const int* __restrict__ src,
                           const int* __restrict__ dst, u64* __restrict__ pkdeg,
                           float* __restrict__ odeg, int* __restrict__ rank, int e) {
    int i = blockIdx.x * blockDim.x + threadIdx.x;
    if (i < e) {
        float w = ew[i];
        int s = src[i], t = dst[i];
        u64 pk = (1ULL << 44) + (u64)(w * FIXS + 0.5f);
        u64 old = atomicAdd(&pkdeg[t], pk);
        rank[i] = (int)(old >> 44);
        atomicAdd(&odeg[s], w);
    }
}

// ---- pad feat (stride 50 fp32) -> xp (stride 64 fp16, zeros in pad) ----
__global__ void k_pad(const float* __restrict__ feat, __half* __restrict__ xp, int n) {
    int i = blockIdx.x * blockDim.x + threadIdx.x;
    if (i < n * PADH) {
        int node = i >> 6, col = i & 63;
        xp[i] = (col < D) ? __float2half_rn(feat[node * D + col]) : __half(0.0f);
    }
}

// ---- unpack: cnt, isi = rsqrt(ideg); iso = rsqrt(odeg) in place ----
__global__ void k_post(const u64* __restrict__ pkdeg, float* __restrict__ odeg,
                       float* __restrict__ isi, int* __restrict__ cnt, int n) {
    int i = blockIdx.x * blockDim.x + threadIdx.x;
    if (i < n) {
        u64 p = pkdeg[i];
        cnt[i] = (int)(p >> 44);
        isi[i] = rsqrtf((float)(p & MASK44) * INV_FIXS);
        odeg[i] = rsqrtf(odeg[i]);   // becomes iso
    }
}

// ---- exclusive scan of cnt -> rowptr ----
__global__ void k_scan1(const int* __restrict__ cnt, int* __restrict__ rowptr,
                        int* __restrict__ bsum, int n) {
    __shared__ int s[SCAN_B];
    int i = blockIdx.x * SCAN_B + threadIdx.x;
    int v = (i < n) ? cnt[i] : 0;
    s[threadIdx.x] = v; __syncthreads();
    for (int off = 1; off < SCAN_B; off <<= 1) {
        int t = (threadIdx.x >= (unsigned)off) ? s[threadIdx.x - off] : 0;
        __syncthreads();
        s[threadIdx.x] += t; __syncthreads();
    }
    if (i < n) rowptr[i] = s[threadIdx.x] - v;          // exclusive
    if (threadIdx.x == SCAN_B - 1) bsum[blockIdx.x] = s[threadIdx.x];
}

__global__ void k_scan2(int* __restrict__ bsum, int nb) {
    __shared__ int s[SCAN_B];
    int v = (threadIdx.x < (unsigned)nb) ? bsum[threadIdx.x] : 0;
    s[threadIdx.x] = v; __syncthreads();
    for (int off = 1; off < SCAN_B; off <<= 1) {
        int t = (threadIdx.x >= (unsigned)off) ? s[threadIdx.x - off] : 0;
        __syncthreads();
        s[threadIdx.x] += t; __syncthreads();
    }
    if (threadIdx.x < (unsigned)nb) bsum[threadIdx.x] = s[threadIdx.x] - v;  // exclusive
}

__global__ void k_scan3(int* __restrict__ rowptr, const int* __restrict__ bsum, int n) {
    int i = blockIdx.x * SCAN_B + threadIdx.x;
    if (i < n) rowptr[i] += bsum[blockIdx.x];
}

// ---- scatter edges into dst-CSR: NO atomics (rank from histogram) ----
__global__ void k_scatter(const float* __restrict__ ew, const int* __restrict__ src,
                          const int* __restrict__ dst, const float* __restrict__ iso,
                          const float* __restrict__ isi, const int* __restrict__ rowptr,
                          const int* __restrict__ rank, u64* __restrict__ pe, int e) {
    int i = blockIdx.x * blockDim.x + threadIdx.x;
    if (i < e) {
        int s = src[i], t = dst[i];
        int pos = rowptr[t] + rank[i];
        float wv = ew[i] * iso[s] * isi[t];
        pe[pos] = (u64)(unsigned)s | ((u64)__float_as_uint(wv) << 32);
    }
}

// ---- fused iteration: 8 edge-slots x 8 lanes x 16B gathers + prox ----
__global__ void k_iter(const int* __restrict__ rowptr, const int* __restrict__ cnt,
                       const u64* __restrict__ pe, const __half* __restrict__ xin,
                       const float* __restrict__ feat, const float* __restrict__ iso,
                       const float* __restrict__ isi, __half* __restrict__ hout,
                       float* __restrict__ fout, int n, int final_iter) {
    int lane = threadIdx.x & 63;
    int node = blockIdx.x * (blockDim.x >> 6) + (threadIdx.x >> 6);
    if (node >= n) return;

    int slot  = lane >> 3;           // edge slot 0..7
    int chunk = lane & 7;            // 8-feature chunk 0..7

    float a0 = 0.f, a1 = 0.f, a2 = 0.f, a3 = 0.f;
    float a4 = 0.f, a5 = 0.f, a6 = 0.f, a7 = 0.f;

    int beg = rowptr[node], m = cnt[node];

    for (int j0 = 0; j0 < m; j0 += 64) {
        int mm = m - j0; if (mm > 64) mm = 64;
        int c = 0; float ww = 0.0f;
        if (lane < mm) {
            u64 p = pe[beg + j0 + lane];
            c  = (int)(unsigned)(p & 0xffffffffULL);
            ww = __uint_as_float((unsigned)(p >> 32));
        }
        for (int jj = 0; jj < mm; jj += 8) {
            int idx = jj + slot;                 // < 64 always
            int   s = __shfl(c,  idx, 64);
            float w = __shfl(ww, idx, 64);
            if (w != 0.0f) {                     // skips junk tail slots too
                uint4 u = *(const uint4*)(xin + ((size_t)s << 6) + (chunk << 3));
                const __half2* hp = (const __half2*)&u;
                float2 f0 = __half22float2(hp[0]);
                float2 f1 = __half22float2(hp[1]);
                float2 f2 = __half22float2(hp[2]);
                float2 f3 = __half22float2(hp[3]);
                a0 = fmaf(w, f0.x, a0); a1 = fmaf(w, f0.y, a1);
                a2 = fmaf(w, f1.x, a2); a3 = fmaf(w, f1.y, a3);
                a4 = fmaf(w, f2.x, a4); a5 = fmaf(w, f2.y, a5);
                a6 = fmaf(w, f3.x, a6); a7 = fmaf(w, f3.y, a7);
            }
        }
    }

    // combine across the 8 slots (fixed chunk): xor masks 8,16,32
    #pragma unroll
    for (int msk = 8; msk <= 32; msk <<= 1) {
        a0 += __shfl_xor(a0, msk, 64); a1 += __shfl_xor(a1, msk, 64);
        a2 += __shfl_xor(a2, msk, 64); a3 += __shfl_xor(a3, msk, 64);
        a4 += __shfl_xor(a4, msk, 64); a5 += __shfl_xor(a5, msk, 64);
        a6 += __shfl_xor(a6, msk, 64); a7 += __shfl_xor(a7, msk, 64);
    }

    // self-loop (uniform across all lanes; groups stay identical)
    float selfw = iso[node] * isi[node];
    {
        uint4 u = *(const uint4*)(xin + ((size_t)node << 6) + (chunk << 3));
        const __half2* hp = (const __half2*)&u;
        float2 f0 = __half22float2(hp[0]);
        float2 f1 = __half22float2(hp[1]);
        float2 f2 = __half22float2(hp[2]);
        float2 f3 = __half22float2(hp[3]);
        a0 = fmaf(selfw, f0.x, a0); a1 = fmaf(selfw, f0.y, a1);
        a2 = fmaf(selfw, f1.x, a2); a3 = fmaf(selfw, f1.y, a3);
        a4 = fmaf(selfw, f2.x, a4); a5 = fmaf(selfw, f2.y, a5);
        a6 = fmaf(selfw, f3.x, a6); a7 = fmaf(selfw, f3.y, a7);
    }

    // feat (fp32, stride 50): features 8*chunk .. 8*chunk+7, zero past 49
    float f[8] = {0.f, 0.f, 0.f, 0.f, 0.f, 0.f, 0.f, 0.f};
    int fb = chunk << 3;
    #pragma unroll
    for (int k = 0; k < 4; ++k) {
        int ff = fb + (k << 1);
        if (ff + 1 < D) {            // D even -> pairs fully valid or invalid
            float2 v = *(const float2*)(feat + (size_t)node * D + ff);
            f[k * 2] = v.x; f[k * 2 + 1] = v.y;
        }
    }

    float d0 = a0 - f[0], d1 = a1 - f[1], d2 = a2 - f[2], d3 = a3 - f[3];
    float d4 = a4 - f[4], d5 = a5 - f[5], d6 = a6 - f[6], d7 = a7 - f[7];
    // pad features: a==0, f==0 -> d==0 automatically

    float ssum = d0*d0 + d1*d1 + d2*d2 + d3*d3 + d4*d4 + d5*d5 + d6*d6 + d7*d7;
    ssum += __shfl_xor(ssum, 1, 64);
    ssum += __shfl_xor(ssum, 2, 64);
    ssum += __shfl_xor(ssum, 4, 64);
    float norm = sqrtf(ssum);
    float sc = (norm > 0.0f) ? fmaxf(norm - GLAM, 0.0f) / norm : 0.0f;

    if (lane < 8) {                  // slot 0 writes
        float o0 = f[0] + sc * d0, o1 = f[1] + sc * d1;
        float o2 = f[2] + sc * d2, o3 = f[3] + sc * d3;
        float o4 = f[4] + sc * d4, o5 = f[5] + sc * d5;
        float o6 = f[6] + sc * d6, o7 = f[7] + sc * d7;
        if (!final_iter) {
            __half2 h0 = __float22half2_rn(make_float2(o0, o1));
            __half2 h1 = __float22half2_rn(make_float2(o2, o3));
            __half2 h2 = __float22half2_rn(make_float2(o4, o5));
            __half2 h3 = __float22half2_rn(make_float2(o6, o7));
            uint4 u;
            u.x = *(unsigned*)&h0; u.y = *(unsigned*)&h1;
            u.z = *(unsigned*)&h2; u.w = *(unsigned*)&h3;
            *(uint4*)(hout + ((size_t)node << 6) + (chunk << 3)) = u;
        } else {
            float o[8] = {o0, o1, o2, o3, o4, o5, o6, o7};
            #pragma unroll
            for (int k = 0; k < 4; ++k) {
                int ff = fb + (k << 1);
                if (ff + 1 < D) {
                    float2 v; v.x = o[k * 2]; v.y = o[k * 2 + 1];
                    *(float2*)(fout + (size_t)node * D + ff) = v;
                }
            }
        }
    }
}

extern "C" void kernel_launch(void* const* d_in, const int* in_sizes, int n_in,
                              void* d_out, int out_size, void* d_ws, size_t ws_size,
                              hipStream_t stream) {
    const float* feat = (const float*)d_in[0];
    const float* ew   = (const float*)d_in[1];
    const int* src = (const int*)d_in[2];
    const int* dst = (const int*)d_in[3];

    const int nd = in_sizes[0];      // N * D
    const int n  = nd / D;           // N nodes
    const int e  = in_sizes[1];      // E edges
    const int np = n * PADH;         // padded fp16 element count

    // workspace layout: 128B-aligned fp16 buffers first
    __half* xpA    = (__half*)d_ws;          // np (fp16, rows 128B-aligned)
    __half* xpB    = xpA + np;               // np
    u64*    pkdeg  = (u64*)(xpB + np);       // n
    u64*    pe     = pkdeg + n;              // e  (packed col|wv)
    float*  odeg   = (float*)(pe + e);       // n  -> iso after k_post
    float*  isi    = odeg + n;               // n
    int*    cnt    = (int*)(isi + n);        // n
    int*    rowptr = cnt + n;                // n
    int*    rank   = rowptr + n;             // e
    int*    bsum   = rank + e;               // 128
    float*  out    = (float*)d_out;

    const int B = 256;
    const int gN = (n + B - 1) / B;
    const int gE = (e + B - 1) / B;
    const int gP = (np + B - 1) / B;
    const int NB = (n + SCAN_B - 1) / SCAN_B;

    k_init<<<gN, B, 0, stream>>>(pkdeg, odeg, n);
    k_deg_hist<<<gE, B, 0, stream>>>(ew, src, dst, pkdeg, odeg, rank, e);
    k_pad<<<gP, B, 0, stream>>>(feat, xpA, n);
    k_post<<<gN, B, 0, stream>>>(pkdeg, odeg, isi, cnt, n);
    k_scan1<<<NB, SCAN_B, 0, stream>>>(cnt, rowptr, bsum, n);
    k_scan2<<<1, SCAN_B, 0, stream>>>(bsum, NB);
    k_scan3<<<NB, SCAN_B, 0, stream>>>(rowptr, bsum, n);
    k_scatter<<<gE, B, 0, stream>>>(ew, src, dst, odeg, isi, rowptr, rank, pe, e);

    const int wavesPerBlock = B / 64;            // 4
    const int iterGrid = (n + wavesPerBlock - 1) / wavesPerBlock;

    // iter1: xpA -> xpB ; iter2: xpB -> xpA ; iter3: xpA -> d_out (fp32)
    k_iter<<<iterGrid, B, 0, stream>>>(rowptr, cnt, pe, xpA, feat, odeg, isi, xpB, out, n, 0);
    k_iter<<<iterGrid, B, 0, stream>>>(rowptr, cnt, pe, xpB, feat, odeg, isi, xpA, out, n, 0);
    k_iter<<<iterGrid, B, 0, stream>>>(rowptr, cnt, pe, xpA, feat, odeg, isi, xpA, out, n, 1);
}